// Round 1
// baseline (2737.821 us; speedup 1.0000x reference)
//
#include <hip/hip_runtime.h>

typedef unsigned short u16;
typedef __attribute__((ext_vector_type(8))) short bf16x8;
typedef __attribute__((ext_vector_type(4))) float f32x4;

#define TOK  8192
#define HD   2048
#define FFD  8192
#define NEXP 4

__device__ __forceinline__ u16 f2bf(float f){
  unsigned u = __float_as_uint(f);
  u += 0x7fffu + ((u >> 16) & 1u);
  return (u16)(u >> 16);
}

__device__ __forceinline__ float gelu_tanh(float x){
  float u = 0.7978845608028654f * (x + 0.044715f * x * x * x);
  return 0.5f * x * (1.0f + tanhf(u));
}

__device__ __forceinline__ void gload_lds16(const void* g, void* l){
  __builtin_amdgcn_global_load_lds((const __attribute__((address_space(1))) void*)g,
                                   (__attribute__((address_space(3))) void*)l, 16, 0, 0);
}

__device__ __forceinline__ f32x4 mfma_bf16(bf16x8 a, bf16x8 b, f32x4 c){
  asm("v_mfma_f32_16x16x32_bf16 %0, %1, %2, %0" : "+v"(c) : "v"(a), "v"(b));
  return c;
}

// ---------------- conversions ----------------
__global__ __launch_bounds__(256) void cvt_to_bf16(const float* __restrict__ in,
                                                   u16* __restrict__ out, int n4){
  int i = blockIdx.x * 256 + threadIdx.x;
  if (i >= n4) return;
  float4 v = ((const float4*)in)[i];
  ushort4 o;
  o.x = f2bf(v.x); o.y = f2bf(v.y); o.z = f2bf(v.z); o.w = f2bf(v.w);
  ((ushort4*)out)[i] = o;
}

// in [R][C] f32  ->  out [C][R] bf16
__global__ __launch_bounds__(256) void transpose_cvt(const float* __restrict__ in,
                                                     u16* __restrict__ out, int R, int C){
  __shared__ float tile[64][65];
  int tx = threadIdx.x & 63;
  int ty = threadIdx.x >> 6;
  size_t r0 = (size_t)blockIdx.y * 64;
  size_t c0 = (size_t)blockIdx.x * 64;
  #pragma unroll
  for (int i = ty; i < 64; i += 4)
    tile[i][tx] = in[(r0 + i) * C + (c0 + tx)];
  __syncthreads();
  #pragma unroll
  for (int i = ty; i < 64; i += 4)
    out[(c0 + i) * R + (r0 + tx)] = f2bf(tile[tx][i]);
}

// ---------------- router ----------------
__global__ __launch_bounds__(256) void router_kernel(
    const float* __restrict__ X, const float* __restrict__ wg, const float* __restrict__ bg,
    float* __restrict__ probs, int* __restrict__ topi, float* __restrict__ gatew){
  int t = blockIdx.x;
  const float* x = X + (size_t)t * HD;
  float a0 = 0.f, a1 = 0.f, a2 = 0.f, a3 = 0.f;
  for (int h = threadIdx.x; h < HD; h += 256){
    float xv = x[h];
    float4 w = ((const float4*)wg)[h];       // wg[h][0..3]
    a0 += xv * w.x; a1 += xv * w.y; a2 += xv * w.z; a3 += xv * w.w;
  }
  __shared__ float red[4][256];
  red[0][threadIdx.x] = a0; red[1][threadIdx.x] = a1;
  red[2][threadIdx.x] = a2; red[3][threadIdx.x] = a3;
  __syncthreads();
  for (int s = 128; s > 0; s >>= 1){
    if (threadIdx.x < (unsigned)s){
      #pragma unroll
      for (int e = 0; e < 4; e++) red[e][threadIdx.x] += red[e][threadIdx.x + s];
    }
    __syncthreads();
  }
  if (threadIdx.x == 0){
    float l[4], p[4];
    #pragma unroll
    for (int e = 0; e < 4; e++) l[e] = red[e][0] + bg[e];
    float mx = fmaxf(fmaxf(l[0], l[1]), fmaxf(l[2], l[3]));
    float s = 0.f;
    #pragma unroll
    for (int e = 0; e < 4; e++){ p[e] = expf(l[e] - mx); s += p[e]; }
    #pragma unroll
    for (int e = 0; e < 4; e++){ p[e] /= s; probs[t * 4 + e] = p[e]; }
    int e0 = 0;
    for (int e = 1; e < 4; e++) if (p[e] > p[e0]) e0 = e;          // ties -> lowest idx (jax)
    int e1 = -1;
    for (int e = 0; e < 4; e++){ if (e == e0) continue; if (e1 < 0 || p[e] > p[e1]) e1 = e; }
    float g = p[e0] + p[e1];
    topi[t * 2] = e0; topi[t * 2 + 1] = e1;
    #pragma unroll
    for (int e = 0; e < 4; e++)
      gatew[(size_t)e * TOK + t] = (e == e0) ? p[e0] / g : (e == e1) ? p[e1] / g : 0.f;
  }
}

// ---------------- aux loss (deterministic single-block reduce) ----------------
__global__ __launch_bounds__(256) void aux_kernel(const float* __restrict__ probs,
                                                  const int* __restrict__ topi,
                                                  float* __restrict__ out_aux){
  __shared__ float sp[4][256];
  __shared__ float sc[4][256];
  float p[4] = {0,0,0,0}, c[4] = {0,0,0,0};
  for (int t = threadIdx.x; t < TOK; t += 256){
    #pragma unroll
    for (int e = 0; e < 4; e++) p[e] += probs[t * 4 + e];
    c[topi[t * 2]]     += 1.f;
    c[topi[t * 2 + 1]] += 1.f;
  }
  #pragma unroll
  for (int e = 0; e < 4; e++){ sp[e][threadIdx.x] = p[e]; sc[e][threadIdx.x] = c[e]; }
  __syncthreads();
  for (int s = 128; s > 0; s >>= 1){
    if (threadIdx.x < (unsigned)s){
      #pragma unroll
      for (int e = 0; e < 4; e++){
        sp[e][threadIdx.x] += sp[e][threadIdx.x + s];
        sc[e][threadIdx.x] += sc[e][threadIdx.x + s];
      }
    }
    __syncthreads();
  }
  if (threadIdx.x == 0){
    float aux = 0.f;
    #pragma unroll
    for (int e = 0; e < 4; e++)
      aux += (sc[e][0] / (float)(TOK * 2)) * (sp[e][0] / (float)TOK);
    *out_aux = 4.f * aux;
  }
}

// ---------------- MFMA GEMM: C = A @ BT^T, A[MxK], BT[NxK], bf16 in / f32 acc ----------------
// EPI 0: Hout = bf16(gelu(C + bias))       EPI 1: Cout = (acc? Cout:0) + gate[row]*(C + bias)
#define BM 128
#define BN 128
#define BK 64

template<int EPI>
__global__ __launch_bounds__(256) void gemm_bt(
    const u16* __restrict__ A, const u16* __restrict__ BT,
    int M, int N, int K,
    const float* __restrict__ bias,
    u16* __restrict__ Hout,
    const float* __restrict__ gate,
    float* __restrict__ Cout,
    int accumulate){
  __shared__ __align__(16) u16 As[BM * BK];
  __shared__ __align__(16) u16 Bs[BN * BK];

  const int tid  = threadIdx.x;
  const int lane = tid & 63;
  const int wid  = tid >> 6;          // 4 waves, 2x2
  const int wr   = wid >> 1;
  const int wc   = wid & 1;
  const size_t brow = (size_t)blockIdx.y * BM;
  const size_t bcol = (size_t)blockIdx.x * BN;

  const int srow = lane >> 3;         // 0..7 row within 8-row chunk
  const int scol = (lane & 7) * 8;    // elem col within BK (16B granules)
  const int r = lane & 15;
  const int h = lane >> 4;

  f32x4 acc[4][4];
  #pragma unroll
  for (int m = 0; m < 4; m++)
    #pragma unroll
    for (int n = 0; n < 4; n++) acc[m][n] = (f32x4){0.f, 0.f, 0.f, 0.f};

  for (int kt = 0; kt < K; kt += BK){
    __syncthreads();
    #pragma unroll
    for (int i = 0; i < 4; i++){
      const int c = wid * 4 + i;                       // 16 chunks of 8 rows x 1KB
      gload_lds16(A  + (brow + c * 8 + srow) * (size_t)K + kt + scol, (char*)As + c * 1024);
      gload_lds16(BT + (bcol + c * 8 + srow) * (size_t)K + kt + scol, (char*)Bs + c * 1024);
    }
    __syncthreads();                                   // drains vmcnt before reads
    #pragma unroll
    for (int kk = 0; kk < BK; kk += 32){
      bf16x8 av[4], bv[4];
      #pragma unroll
      for (int m = 0; m < 4; m++)
        av[m] = *(const bf16x8*)(As + (wr * 64 + m * 16 + r) * BK + kk + h * 8);
      #pragma unroll
      for (int n = 0; n < 4; n++)
        bv[n] = *(const bf16x8*)(Bs + (wc * 64 + n * 16 + r) * BK + kk + h * 8);
      #pragma unroll
      for (int m = 0; m < 4; m++)
        #pragma unroll
        for (int n = 0; n < 4; n++)
          acc[m][n] = mfma_bf16(av[m], bv[n], acc[m][n]);
    }
  }

  // epilogue: D[row=(lane>>4)*4+j][col=lane&15] per 16x16 fragment (m91-verified)
  const int cl = lane & 15;
  const int rg = (lane >> 4) * 4;
  const size_t r0 = brow + (size_t)wr * 64;
  const size_t c0 = bcol + (size_t)wc * 64;
  float bvs[4];
  #pragma unroll
  for (int n = 0; n < 4; n++) bvs[n] = bias[c0 + n * 16 + cl];

  #pragma unroll
  for (int m = 0; m < 4; m++){
    const size_t rowb = r0 + m * 16 + rg;
    if (EPI == 0){
      #pragma unroll
      for (int n = 0; n < 4; n++){
        const size_t col = c0 + n * 16 + cl;
        #pragma unroll
        for (int j = 0; j < 4; j++){
          float y = acc[m][n][j] + bvs[n];
          Hout[(rowb + j) * (size_t)N + col] = f2bf(gelu_tanh(y));
        }
      }
    } else {
      float gv[4];
      #pragma unroll
      for (int j = 0; j < 4; j++) gv[j] = gate[rowb + j];
      #pragma unroll
      for (int n = 0; n < 4; n++){
        const size_t col = c0 + n * 16 + cl;
        #pragma unroll
        for (int j = 0; j < 4; j++){
          float y = acc[m][n][j] + bvs[n];
          const size_t idx = (rowb + j) * (size_t)N + col;
          float prev = accumulate ? Cout[idx] : 0.f;
          Cout[idx] = prev + gv[j] * y;
        }
      }
    }
  }
}

// ---------------- host ----------------
extern "C" void kernel_launch(void* const* d_in, const int* in_sizes, int n_in,
                              void* d_out, int out_size, void* d_ws, size_t ws_size,
                              hipStream_t stream){
  const float* X  = (const float*)d_in[0];
  const float* wg = (const float*)d_in[1];
  const float* bg = (const float*)d_in[2];
  const float* w1 = (const float*)d_in[3];
  const float* b1 = (const float*)d_in[4];
  const float* w2 = (const float*)d_in[5];
  const float* b2 = (const float*)d_in[6];
  float* out = (float*)d_out;

  char* ws = (char*)d_ws;
  size_t off = 0;
  auto alloc = [&](size_t b) -> char* {
    char* p = ws + off;
    off = (off + b + 255) & ~(size_t)255;
    return p;
  };
  u16*   Xb    = (u16*)  alloc((size_t)TOK * HD * 2);
  u16*   W1T   = (u16*)  alloc((size_t)FFD * HD * 2);   // per-expert, reused
  u16*   W2T   = (u16*)  alloc((size_t)HD * FFD * 2);   // per-expert, reused
  float* probs = (float*)alloc((size_t)TOK * 4 * 4);
  int*   topi  = (int*)  alloc((size_t)TOK * 2 * 4);
  float* gatew = (float*)alloc((size_t)NEXP * TOK * 4);
  size_t remain = (ws_size > off) ? (ws_size - off) : 0;
  size_t ch = remain / ((size_t)FFD * 2);
  ch = (ch / 128) * 128;
  if (ch > TOK) ch = TOK;
  if (ch < 128) ch = 128;
  u16* Hb = (u16*)alloc(ch * (size_t)FFD * 2);

  cvt_to_bf16<<<(TOK * HD / 4 + 255) / 256, 256, 0, stream>>>(X, Xb, TOK * HD / 4);
  router_kernel<<<TOK, 256, 0, stream>>>(X, wg, bg, probs, topi, gatew);
  aux_kernel<<<1, 256, 0, stream>>>(probs, topi, out + (out_size - 1));

  for (int e = 0; e < NEXP; ++e){
    transpose_cvt<<<dim3(FFD / 64, HD / 64), 256, 0, stream>>>(
        w1 + (size_t)e * HD * FFD, W1T, HD, FFD);
    transpose_cvt<<<dim3(HD / 64, FFD / 64), 256, 0, stream>>>(
        w2 + (size_t)e * FFD * HD, W2T, FFD, HD);
    for (int m0 = 0; m0 < TOK; m0 += (int)ch){
      int rows = TOK - m0 < (int)ch ? TOK - m0 : (int)ch;
      gemm_bt<0><<<dim3(FFD / 128, rows / 128), 256, 0, stream>>>(
          Xb + (size_t)m0 * HD, W1T, rows, FFD, HD,
          b1 + (size_t)e * FFD, Hb, nullptr, nullptr, 0);
      gemm_bt<1><<<dim3(HD / 128, rows / 128), 256, 0, stream>>>(
          Hb, W2T, rows, HD, FFD,
          b2 + (size_t)e * HD, nullptr,
          gatew + (size_t)e * TOK + m0, out + (size_t)m0 * HD, e > 0);
    }
  }
}

// Round 2
// 1954.646 us; speedup vs baseline: 1.4007x; 1.4007x over previous
//
#include <hip/hip_runtime.h>

typedef unsigned short u16;
typedef __attribute__((ext_vector_type(8))) short bf16x8;
typedef __attribute__((ext_vector_type(4))) float f32x4;

#define TOK  8192
#define HD   2048
#define FFD  8192
#define NEXP 4

__device__ __forceinline__ u16 f2bf(float f){
  unsigned u = __float_as_uint(f);
  u += 0x7fffu + ((u >> 16) & 1u);
  return (u16)(u >> 16);
}

__device__ __forceinline__ float gelu_tanh(float x){
  float u = 0.7978845608028654f * (x + 0.044715f * x * x * x);
  return 0.5f * x * (1.0f + tanhf(u));
}

__device__ __forceinline__ void gload_lds16(const void* g, void* l){
  __builtin_amdgcn_global_load_lds((const __attribute__((address_space(1))) void*)g,
                                   (__attribute__((address_space(3))) void*)l, 16, 0, 0);
}

__device__ __forceinline__ f32x4 mfma_bf16(bf16x8 a, bf16x8 b, f32x4 c){
  asm("v_mfma_f32_16x16x32_bf16 %0, %1, %2, %0" : "+v"(c) : "v"(a), "v"(b));
  return c;
}

// ---------------- conversions ----------------
__global__ __launch_bounds__(256) void cvt_to_bf16(const float* __restrict__ in,
                                                   u16* __restrict__ out, int n4){
  int i = blockIdx.x * 256 + threadIdx.x;
  if (i >= n4) return;
  float4 v = ((const float4*)in)[i];
  ushort4 o;
  o.x = f2bf(v.x); o.y = f2bf(v.y); o.z = f2bf(v.z); o.w = f2bf(v.w);
  ((ushort4*)out)[i] = o;
}

// in [R][C] f32  ->  out [C][R] bf16
__global__ __launch_bounds__(256) void transpose_cvt(const float* __restrict__ in,
                                                     u16* __restrict__ out, int R, int C){
  __shared__ float tile[64][65];
  int tx = threadIdx.x & 63;
  int ty = threadIdx.x >> 6;
  size_t r0 = (size_t)blockIdx.y * 64;
  size_t c0 = (size_t)blockIdx.x * 64;
  #pragma unroll
  for (int i = ty; i < 64; i += 4)
    tile[i][tx] = in[(r0 + i) * C + (c0 + tx)];
  __syncthreads();
  #pragma unroll
  for (int i = ty; i < 64; i += 4)
    out[(c0 + i) * R + (r0 + tx)] = f2bf(tile[tx][i]);
}

// ---------------- router ----------------
__global__ __launch_bounds__(256) void router_kernel(
    const float* __restrict__ X, const float* __restrict__ wg, const float* __restrict__ bg,
    float* __restrict__ probs, int* __restrict__ topi, float* __restrict__ gatew){
  int t = blockIdx.x;
  const float* x = X + (size_t)t * HD;
  float a0 = 0.f, a1 = 0.f, a2 = 0.f, a3 = 0.f;
  for (int h = threadIdx.x; h < HD; h += 256){
    float xv = x[h];
    float4 w = ((const float4*)wg)[h];       // wg[h][0..3]
    a0 += xv * w.x; a1 += xv * w.y; a2 += xv * w.z; a3 += xv * w.w;
  }
  __shared__ float red[4][256];
  red[0][threadIdx.x] = a0; red[1][threadIdx.x] = a1;
  red[2][threadIdx.x] = a2; red[3][threadIdx.x] = a3;
  __syncthreads();
  for (int s = 128; s > 0; s >>= 1){
    if (threadIdx.x < (unsigned)s){
      #pragma unroll
      for (int e = 0; e < 4; e++) red[e][threadIdx.x] += red[e][threadIdx.x + s];
    }
    __syncthreads();
  }
  if (threadIdx.x == 0){
    float l[4], p[4];
    #pragma unroll
    for (int e = 0; e < 4; e++) l[e] = red[e][0] + bg[e];
    float mx = fmaxf(fmaxf(l[0], l[1]), fmaxf(l[2], l[3]));
    float s = 0.f;
    #pragma unroll
    for (int e = 0; e < 4; e++){ p[e] = expf(l[e] - mx); s += p[e]; }
    #pragma unroll
    for (int e = 0; e < 4; e++){ p[e] /= s; probs[t * 4 + e] = p[e]; }
    int e0 = 0;
    for (int e = 1; e < 4; e++) if (p[e] > p[e0]) e0 = e;          // ties -> lowest idx (jax)
    int e1 = -1;
    for (int e = 0; e < 4; e++){ if (e == e0) continue; if (e1 < 0 || p[e] > p[e1]) e1 = e; }
    float g = p[e0] + p[e1];
    topi[t * 2] = e0; topi[t * 2 + 1] = e1;
    #pragma unroll
    for (int e = 0; e < 4; e++)
      gatew[(size_t)e * TOK + t] = (e == e0) ? p[e0] / g : (e == e1) ? p[e1] / g : 0.f;
  }
}

// ---------------- expert token lists ----------------
__global__ __launch_bounds__(256) void build_lists(const int* __restrict__ topi,
                                                   int* __restrict__ cnt,
                                                   int* __restrict__ lists){
  int t = blockIdx.x * 256 + threadIdx.x;
  if (t >= TOK) return;
  #pragma unroll
  for (int k = 0; k < 2; k++){
    int e = topi[t * 2 + k];
    int p = atomicAdd(cnt + e, 1);
    lists[e * TOK + p] = t;    // order nondeterministic; output is row-independent
  }
}

// ---------------- aux loss (deterministic single-block reduce) ----------------
__global__ __launch_bounds__(256) void aux_kernel(const float* __restrict__ probs,
                                                  const int* __restrict__ topi,
                                                  float* __restrict__ out_aux){
  __shared__ float sp[4][256];
  __shared__ float sc[4][256];
  float p[4] = {0,0,0,0}, c[4] = {0,0,0,0};
  for (int t = threadIdx.x; t < TOK; t += 256){
    #pragma unroll
    for (int e = 0; e < 4; e++) p[e] += probs[t * 4 + e];
    c[topi[t * 2]]     += 1.f;
    c[topi[t * 2 + 1]] += 1.f;
  }
  #pragma unroll
  for (int e = 0; e < 4; e++){ sp[e][threadIdx.x] = p[e]; sc[e][threadIdx.x] = c[e]; }
  __syncthreads();
  for (int s = 128; s > 0; s >>= 1){
    if (threadIdx.x < (unsigned)s){
      #pragma unroll
      for (int e = 0; e < 4; e++){
        sp[e][threadIdx.x] += sp[e][threadIdx.x + s];
        sc[e][threadIdx.x] += sc[e][threadIdx.x + s];
      }
    }
    __syncthreads();
  }
  if (threadIdx.x == 0){
    float aux = 0.f;
    #pragma unroll
    for (int e = 0; e < 4; e++)
      aux += (sc[e][0] / (float)(TOK * 2)) * (sp[e][0] / (float)TOK);
    *out_aux = 4.f * aux;
  }
}

// ---------------- gathered MFMA GEMM over one expert's token list ----------------
// EPI 0: A = Xb gathered by rowidx; Hout[chunk-local row] = bf16(gelu(acc+bias))
// EPI 1: A = Hb (chunk-local rows); Cout[rowidx[row]] += gate[rowidx[row]] * (acc+bias)
#define BM 128
#define BN 128
#define BK 64

template<int EPI>
__global__ __launch_bounds__(256) void gemm_moe(
    const u16* __restrict__ A, const u16* __restrict__ BT,
    const int* __restrict__ rowidx, const int* __restrict__ cntp,
    int m0, int N, int K,
    const float* __restrict__ bias,
    u16* __restrict__ Hout,
    const float* __restrict__ gate,
    float* __restrict__ Cout){
  const int Mv = *cntp;                       // expert's token count
  const int browg = m0 + blockIdx.y * BM;     // expert-local global row of this block
  if (browg >= Mv) return;

  __shared__ __align__(16) u16 As[BM * BK];
  __shared__ __align__(16) u16 Bs[BN * BK];

  const int tid  = threadIdx.x;
  const int lane = tid & 63;
  const int wid  = tid >> 6;          // 4 waves, 2x2
  const int wr   = wid >> 1;
  const int wc   = wid & 1;
  const size_t bcol = (size_t)blockIdx.x * BN;

  const int srow = lane >> 3;         // 0..7 row within 8-row chunk
  const int scol = (lane & 7) * 8;    // elem col within BK (16B granules)
  const int r = lane & 15;
  const int h = lane >> 4;

  // staging source pointers — invariant across the K loop
  const u16* aptr[4];
  const u16* bptr[4];
  #pragma unroll
  for (int i = 0; i < 4; i++){
    const int c = wid * 4 + i;
    const int rr = browg + c * 8 + srow;
    int ar;
    if (EPI == 0){
      const int cr = rr < Mv ? rr : Mv - 1;   // clamp pad rows to a valid token
      ar = rowidx[cr];
    } else {
      ar = rr - m0;                           // chunk-local Hb row
    }
    aptr[i] = A + (size_t)ar * K + scol;
    bptr[i] = BT + (bcol + c * 8 + srow) * (size_t)K + scol;
  }

  f32x4 acc[4][4];
  #pragma unroll
  for (int m = 0; m < 4; m++)
    #pragma unroll
    for (int n = 0; n < 4; n++) acc[m][n] = (f32x4){0.f, 0.f, 0.f, 0.f};

  for (int kt = 0; kt < K; kt += BK){
    __syncthreads();
    #pragma unroll
    for (int i = 0; i < 4; i++){
      const int c = wid * 4 + i;
      gload_lds16(aptr[i] + kt, (char*)As + c * 1024);
      gload_lds16(bptr[i] + kt, (char*)Bs + c * 1024);
    }
    __syncthreads();                                   // drains vmcnt before reads
    #pragma unroll
    for (int kk = 0; kk < BK; kk += 32){
      bf16x8 av[4], bv[4];
      #pragma unroll
      for (int m = 0; m < 4; m++)
        av[m] = *(const bf16x8*)(As + (wr * 64 + m * 16 + r) * BK + kk + h * 8);
      #pragma unroll
      for (int n = 0; n < 4; n++)
        bv[n] = *(const bf16x8*)(Bs + (wc * 64 + n * 16 + r) * BK + kk + h * 8);
      #pragma unroll
      for (int m = 0; m < 4; m++)
        #pragma unroll
        for (int n = 0; n < 4; n++)
          acc[m][n] = mfma_bf16(av[m], bv[n], acc[m][n]);
    }
  }

  // epilogue: D[row=(lane>>4)*4+j][col=lane&15] per 16x16 fragment (m91-verified)
  const int cl = lane & 15;
  const int rg = (lane >> 4) * 4;
  const size_t c0 = bcol + (size_t)wc * 64;
  float bvs[4];
  #pragma unroll
  for (int n = 0; n < 4; n++) bvs[n] = bias[c0 + n * 16 + cl];

  #pragma unroll
  for (int m = 0; m < 4; m++){
    const int rowg = browg + wr * 64 + m * 16 + rg;    // expert-local row of j=0
    if (EPI == 0){
      const size_t rowl = (size_t)(rowg - m0);         // chunk-local Hb row
      #pragma unroll
      for (int n = 0; n < 4; n++){
        const size_t col = c0 + n * 16 + cl;
        #pragma unroll
        for (int j = 0; j < 4; j++){
          float y = acc[m][n][j] + bvs[n];
          Hout[(rowl + j) * (size_t)N + col] = f2bf(gelu_tanh(y));
        }
      }
    } else {
      int   tok[4];
      float gv[4];
      #pragma unroll
      for (int j = 0; j < 4; j++){
        const bool v = (rowg + j) < Mv;
        tok[j] = v ? rowidx[rowg + j] : -1;
        gv[j]  = v ? gate[tok[j]] : 0.f;
      }
      #pragma unroll
      for (int n = 0; n < 4; n++){
        const size_t col = c0 + n * 16 + cl;
        #pragma unroll
        for (int j = 0; j < 4; j++){
          if (tok[j] >= 0){
            float y = acc[m][n][j] + bvs[n];
            const size_t idx = (size_t)tok[j] * N + col;
            Cout[idx] += gv[j] * y;     // serialized dispatches + unique tokens -> race-free
          }
        }
      }
    }
  }
}

// ---------------- host ----------------
extern "C" void kernel_launch(void* const* d_in, const int* in_sizes, int n_in,
                              void* d_out, int out_size, void* d_ws, size_t ws_size,
                              hipStream_t stream){
  const float* X  = (const float*)d_in[0];
  const float* wg = (const float*)d_in[1];
  const float* bg = (const float*)d_in[2];
  const float* w1 = (const float*)d_in[3];
  const float* b1 = (const float*)d_in[4];
  const float* w2 = (const float*)d_in[5];
  const float* b2 = (const float*)d_in[6];
  float* out = (float*)d_out;

  char* ws = (char*)d_ws;
  size_t off = 0;
  auto alloc = [&](size_t b) -> char* {
    char* p = ws + off;
    off = (off + b + 255) & ~(size_t)255;
    return p;
  };
  u16*   Xb    = (u16*)  alloc((size_t)TOK * HD * 2);
  u16*   W1T   = (u16*)  alloc((size_t)FFD * HD * 2);   // per-expert, reused
  u16*   W2T   = (u16*)  alloc((size_t)HD * FFD * 2);   // per-expert, reused
  float* probs = (float*)alloc((size_t)TOK * 4 * 4);
  int*   topi  = (int*)  alloc((size_t)TOK * 2 * 4);
  float* gatew = (float*)alloc((size_t)NEXP * TOK * 4);
  int*   cnt   = (int*)  alloc((size_t)NEXP * 4);
  int*   lists = (int*)  alloc((size_t)NEXP * TOK * 4);
  size_t remain = (ws_size > off) ? (ws_size - off) : 0;
  size_t ch = remain / ((size_t)FFD * 2);
  ch = (ch / 128) * 128;
  if (ch > TOK) ch = TOK;
  if (ch < 128) ch = 128;
  u16* Hb = (u16*)alloc(ch * (size_t)FFD * 2);

  hipMemsetAsync(cnt, 0, NEXP * sizeof(int), stream);
  hipMemsetAsync(out, 0, (size_t)TOK * HD * sizeof(float), stream);

  cvt_to_bf16<<<(TOK * HD / 4 + 255) / 256, 256, 0, stream>>>(X, Xb, TOK * HD / 4);
  router_kernel<<<TOK, 256, 0, stream>>>(X, wg, bg, probs, topi, gatew);
  build_lists<<<TOK / 256, 256, 0, stream>>>(topi, cnt, lists);
  aux_kernel<<<1, 256, 0, stream>>>(probs, topi, out + (out_size - 1));

  for (int e = 0; e < NEXP; ++e){
    transpose_cvt<<<dim3(FFD / 64, HD / 64), 256, 0, stream>>>(
        w1 + (size_t)e * HD * FFD, W1T, HD, FFD);
    transpose_cvt<<<dim3(HD / 64, FFD / 64), 256, 0, stream>>>(
        w2 + (size_t)e * FFD * HD, W2T, FFD, HD);
    for (int m0 = 0; m0 < TOK; m0 += (int)ch){
      gemm_moe<0><<<dim3(FFD / 128, (unsigned)(ch / 128)), 256, 0, stream>>>(
          Xb, W1T, lists + e * TOK, cnt + e, m0, FFD, HD,
          b1 + (size_t)e * FFD, Hb, nullptr, nullptr);
      gemm_moe<1><<<dim3(HD / 128, (unsigned)(ch / 128)), 256, 0, stream>>>(
          Hb, W2T, lists + e * TOK, cnt + e, m0, HD, FFD,
          b2 + (size_t)e * HD, nullptr,
          gatew + (size_t)e * TOK, out);
    }
  }
}